// Round 4
// baseline (177.745 us; speedup 1.0000x reference)
//
#include <hip/hip_runtime.h>

#define T_SEQ   4096
#define D_MODEL 1024
#define NH      16
#define HD      64
#define E3      3072
// 0.125 * log2(e): folded into Q in the QKV-GEMM epilogue; softmax uses exp2 directly
#define QSCL    0.18033688011112042f
#define CLMP    14.426950408889634f

using u32x2  = __attribute__((ext_vector_type(2))) unsigned int;
using u32x4  = __attribute__((ext_vector_type(4))) unsigned int;
using u16x4  = __attribute__((ext_vector_type(4))) unsigned short;
using f32x4  = __attribute__((ext_vector_type(4))) float;
using bf16x8 = __attribute__((ext_vector_type(8))) __bf16;

__device__ __forceinline__ unsigned short f2bf(float f){
  unsigned int u = __builtin_bit_cast(unsigned int, f);
  u += 0x7fffu + ((u >> 16) & 1u);          // RNE
  return (unsigned short)(u >> 16);
}

__device__ __forceinline__ void gload_lds16(const void* g, void* l){
  __builtin_amdgcn_global_load_lds((const __attribute__((address_space(1))) void*)g,
                                   (__attribute__((address_space(3))) void*)l, 16, 0, 0);
}

// ---------------- fp32 -> bf16 convert ----------------
__global__ __launch_bounds__(256) void cvt_f32_bf16(const float4* __restrict__ in,
                                                    u16x4* __restrict__ out, int n4){
  int i = blockIdx.x * 256 + threadIdx.x;
  if(i < n4){
    float4 v = in[i];
    u16x4 o = { f2bf(v.x), f2bf(v.y), f2bf(v.z), f2bf(v.w) };
    out[i] = o;
  }
}

// ---------------- C = A * B^T  (A[M,K], B[N,K] row-major, bf16 in, fp32 acc) --------
template<int OUT_BF16, int QSCALE>
__global__ __launch_bounds__(256) void gemm_bt(const unsigned short* __restrict__ A,
                                               const unsigned short* __restrict__ B,
                                               void* __restrict__ Cv,
                                               int M, int N, int K){
  __shared__ unsigned short As[128*32];
  __shared__ unsigned short Bs[128*32];
  const int t    = threadIdx.x;
  const int lane = t & 63;
  const int w    = t >> 6;
  const int brow = blockIdx.y * 128;
  const int bcol = blockIdx.x * 128;
  const int wrow = (w >> 1) * 64;
  const int wcol = (w & 1) * 64;
  const int cc = lane & 15;
  const int gg = lane >> 4;

  f32x4 acc[4][4];
  #pragma unroll
  for(int m=0;m<4;++m)
    #pragma unroll
    for(int n=0;n<4;++n)
      acc[m][n] = (f32x4){0.f,0.f,0.f,0.f};

  const int srow = t >> 2;
  const int sk   = (t & 3) * 8;
  const long aBase = (long)(brow + srow) * K;
  const long bBase = (long)(bcol + srow) * K;

  for(int k0 = 0; k0 < K; k0 += 32){
    __syncthreads();
    gload_lds16(A + aBase + k0 + sk,               As + t*8);
    gload_lds16(A + aBase + 64*(long)K + k0 + sk,  As + 2048 + t*8);
    gload_lds16(B + bBase + k0 + sk,               Bs + t*8);
    gload_lds16(B + bBase + 64*(long)K + k0 + sk,  Bs + 2048 + t*8);
    __syncthreads();

    bf16x8 af[4], bfr[4];
    #pragma unroll
    for(int m=0;m<4;++m)
      af[m]  = *(const bf16x8*)((const char*)As + (wrow + m*16 + cc)*64 + gg*16);
    #pragma unroll
    for(int n=0;n<4;++n)
      bfr[n] = *(const bf16x8*)((const char*)Bs + (wcol + n*16 + cc)*64 + gg*16);
    #pragma unroll
    for(int m=0;m<4;++m)
      #pragma unroll
      for(int n=0;n<4;++n)
        acc[m][n] = __builtin_amdgcn_mfma_f32_16x16x32_bf16(af[m], bfr[n], acc[m][n], 0, 0, 0);
  }

  #pragma unroll
  for(int m=0;m<4;++m){
    #pragma unroll
    for(int n=0;n<4;++n){
      const int row0 = brow + wrow + m*16 + gg*4;
      const int col  = bcol + wcol + n*16 + cc;
      const float sc = (QSCALE && col < D_MODEL) ? QSCL : 1.0f;
      #pragma unroll
      for(int r=0;r<4;++r){
        if constexpr (OUT_BF16 != 0){
          ((unsigned short*)Cv)[(long)(row0 + r)*N + col] = f2bf(acc[m][n][r] * sc);
        } else {
          ((float*)Cv)[(long)(row0 + r)*N + col] = acc[m][n][r];
        }
      }
    }
  }
}

// ---------------- fused causal attention v4 ----------------
// block = (head, q-block PAIR (i, 63-i)) -> uniform 65 MFMA-tile-units per block.
// Union kv loop over the big block's range; small block rides along while kv<=i.
// 4 waves x 16 q-rows each (per q-block). KVBLK=64, double-buffered, registers-only P.
__global__ __launch_bounds__(256, 2) void attn_fused(const unsigned short* __restrict__ qkv,
                                                     unsigned short* __restrict__ aout){
  __shared__ unsigned short Ks[2][64*64];    // K: row=key (128B), chunk c holds d-oct c^(k&7)
  __shared__ unsigned short VTs[2][64*64];   // V^T: row=d (128B), chunk c holds k-oct c^((d>>1)&7)

  const int t    = threadIdx.x;
  const int lane = t & 63;
  const int w    = t >> 6;
  const int cc   = lane & 15;
  const int gg   = lane >> 4;

  const int bid  = blockIdx.x;
  const int pi   = bid >> 4;                 // 0..31
  const int hd   = bid & 15;
  const int qa   = pi;                       // small q-block
  const int qb   = 63 - pi;                  // big q-block
  const int nA   = qa + 1;
  const int nkv  = qb + 1;                   // >= 33
  const int q0A  = qa*64 + w*16;
  const int q0B  = qb*64 + w*16;

  // Q fragments (pre-scaled by 0.125*log2e in GEMM epilogue)
  bf16x8 bqA0 = *(const bf16x8*)(qkv + (long)(q0A+cc)*E3 + hd*HD +      gg*8);
  bf16x8 bqA1 = *(const bf16x8*)(qkv + (long)(q0A+cc)*E3 + hd*HD + 32 + gg*8);
  bf16x8 bqB0 = *(const bf16x8*)(qkv + (long)(q0B+cc)*E3 + hd*HD +      gg*8);
  bf16x8 bqB1 = *(const bf16x8*)(qkv + (long)(q0B+cc)*E3 + hd*HD + 32 + gg*8);

  f32x4 accA[4], accB[4];
  #pragma unroll
  for(int vt=0;vt<4;++vt){ accA[vt] = (f32x4){0.f,0.f,0.f,0.f};
                           accB[vt] = (f32x4){0.f,0.f,0.f,0.f}; }
  float rsA = 0.f, rsB = 0.f;

  // ---- hoisted LDS read pointers (kt/vt/buf become immediate offsets) ----
  const char* kpA  = (const char*)Ks  + cc*128 + ((gg ^ (cc&7)) << 4);
  const char* kpB  = (const char*)Ks  + ((cc*128 + ((gg ^ (cc&7)) << 4)) ^ 64);
  const int   va0  = cc*128 + (((gg>>1) ^ (cc>>1)) << 4) + (gg&1)*8;
  const char* vp00 = (const char*)VTs + va0;          // hh0, k-oct lo
  const char* vp01 = (const char*)VTs + (va0 ^ 32);   // hh0, k-oct hi (+16 k)
  const char* vp10 = (const char*)VTs + (va0 ^ 64);   // hh1, lo
  const char* vp11 = (const char*)VTs + (va0 ^ 96);   // hh1, hi

  // ---- staging precompute ----
  const long tileStride = 64L * E3;
  const int  s0  = t*16,            s1  = 4096 + t*16;
  const int  kr0 = s0 >> 7,         kr1 = s1 >> 7;
  const long kg0 = (long)kr0*E3 + D_MODEL + hd*HD + ((((s0>>4)&7) ^ (kr0&7)))*8;
  const long kg1 = (long)kr1*E3 + D_MODEL + hd*HD + ((((s1>>4)&7) ^ (kr1&7)))*8;
  const int  dp  = t & 31;
  const int  ko  = t >> 5;
  const long vg  = (long)(ko*8)*E3 + 2*D_MODEL + hd*HD + 2*dp;
  char* vwp = (char*)VTs + (2*dp)*128 + ((ko ^ (dp&7)) << 4);

  unsigned int vr[8];

  #define STAGE_K(kb_, BUF) do{                                                    \
    gload_lds16(qkv + kg0 + (kb_)*tileStride, (char*)Ks + (BUF)*8192 + s0);        \
    gload_lds16(qkv + kg1 + (kb_)*tileStride, (char*)Ks + (BUF)*8192 + s1);        \
  }while(0)

  #define VLOAD(kb_) do{                                                           \
    const unsigned short* vb_ = qkv + vg + (kb_)*tileStride;                       \
    _Pragma("unroll")                                                              \
    for(int j=0;j<8;++j) vr[j] = *(const unsigned int*)(vb_ + (long)j*E3);         \
  }while(0)

  #define VWRITE(BUF) do{                                                          \
    u32x4 lo_, hi_;                                                                \
    _Pragma("unroll")                                                              \
    for(int j=0;j<4;++j){                                                          \
      lo_[j] = __builtin_amdgcn_perm(vr[2*j+1], vr[2*j], 0x05040100u);             \
      hi_[j] = __builtin_amdgcn_perm(vr[2*j+1], vr[2*j], 0x07060302u);             \
    }                                                                              \
    *(u32x4*)(vwp + (BUF)*8192      ) = lo_;                                       \
    *(u32x4*)(vwp + (BUF)*8192 + 128) = hi_;                                       \
  }while(0)

  // one q-block's QK -> softmax -> PV for the current kv tile (P stays in registers)
  #define QPART(bq0_, bq1_, acc_, rs_, lastE_, BUF)                                \
  {                                                                                \
    const bool isLast_ = (lastE_);                                                 \
    float pkf[4][4];                                                               \
    _Pragma("unroll")                                                              \
    for(int kt=0; kt<4; ++kt){                                                     \
      if(!isLast_ || kt <= w){                                                     \
        bf16x8 a0 = *(const bf16x8*)(kpA + (BUF)*8192 + kt*2048);                  \
        bf16x8 a1 = *(const bf16x8*)(kpB + (BUF)*8192 + kt*2048);                  \
        __builtin_amdgcn_s_setprio(1);                                             \
        f32x4 s = __builtin_amdgcn_mfma_f32_16x16x32_bf16(a0, bq0_,                \
                    (f32x4){0.f,0.f,0.f,0.f}, 0,0,0);                              \
        s = __builtin_amdgcn_mfma_f32_16x16x32_bf16(a1, bq1_, s, 0,0,0);           \
        __builtin_amdgcn_s_setprio(0);                                             \
        const bool diag_ = isLast_ && (kt == w);                                   \
        _Pragma("unroll")                                                          \
        for(int r=0;r<4;++r){                                                      \
          float sv = fminf(fmaxf(s[r], -CLMP), CLMP);                              \
          float p  = __builtin_exp2f(sv);                                          \
          if(diag_ && (4*gg + r > cc)) p = 0.f;                                    \
          pkf[kt][r] = p;                                                          \
          rs_ += p;                                                                \
        }                                                                          \
      } else {                                                                     \
        _Pragma("unroll")                                                          \
        for(int r=0;r<4;++r) pkf[kt][r] = 0.f;                                     \
      }                                                                            \
    }                                                                              \
    bf16x8 pa0 = (bf16x8){ (__bf16)pkf[0][0],(__bf16)pkf[0][1],(__bf16)pkf[0][2],  \
      (__bf16)pkf[0][3],(__bf16)pkf[1][0],(__bf16)pkf[1][1],(__bf16)pkf[1][2],     \
      (__bf16)pkf[1][3] };                                                         \
    bf16x8 pa1 = (bf16x8){ (__bf16)pkf[2][0],(__bf16)pkf[2][1],(__bf16)pkf[2][2],  \
      (__bf16)pkf[2][3],(__bf16)pkf[3][0],(__bf16)pkf[3][1],(__bf16)pkf[3][2],     \
      (__bf16)pkf[3][3] };                                                         \
    _Pragma("unroll")                                                              \
    for(int hh=0; hh<2; ++hh){                                                     \
      if(!isLast_ || 2*hh <= w){                                                   \
        const char* vl_ = hh ? vp10 : vp00;                                        \
        const char* vh_ = hh ? vp11 : vp01;                                        \
        __builtin_amdgcn_s_setprio(1);                                             \
        _Pragma("unroll")                                                          \
        for(int vt=0; vt<4; ++vt){                                                 \
          u32x2 lo = *(const u32x2*)(vl_ + (BUF)*8192 + vt*2048);                  \
          u32x2 hi = *(const u32x2*)(vh_ + (BUF)*8192 + vt*2048);                  \
          bf16x8 bv = __builtin_bit_cast(bf16x8,(u32x4){lo[0],lo[1],hi[0],hi[1]}); \
          acc_[vt] = __builtin_amdgcn_mfma_f32_16x16x32_bf16(hh ? pa1 : pa0, bv,   \
                       acc_[vt], 0,0,0);                                           \
        }                                                                          \
        __builtin_amdgcn_s_setprio(0);                                             \
      }                                                                            \
    }                                                                              \
  }

  #define TILE(kb_, BUF)                                                           \
  {                                                                                \
    const bool pf_ = ((kb_) + 1 < nkv);                                            \
    if(pf_){ STAGE_K((kb_)+1, (BUF)^1); VLOAD((kb_)+1); }                          \
    QPART(bqB0, bqB1, accB, rsB, (kb_) == nkv-1, BUF);                             \
    if((kb_) < nA) QPART(bqA0, bqA1, accA, rsA, (kb_) == nA-1, BUF);               \
    if(pf_) VWRITE((BUF)^1);                                                       \
    __syncthreads();                                                               \
  }

  STAGE_K(0, 0);
  VLOAD(0);
  VWRITE(0);
  __syncthreads();

  int kv = 0;
  while(kv + 2 <= nkv){
    TILE(kv,   0);
    TILE(kv+1, 1);
    kv += 2;
  }
  if(kv < nkv) TILE(kv, 0);

  #define OUTQ(acc_, rs_, q0_)                                                     \
  {                                                                                \
    float v_ = rs_;                                                                \
    v_ += __shfl_xor(v_, 16);                                                      \
    v_ += __shfl_xor(v_, 32);                                                      \
    _Pragma("unroll")                                                              \
    for(int r=0;r<4;++r){                                                          \
      const float inv_ = 1.0f / __shfl(v_, 4*gg + r);                              \
      const int row_ = (q0_) + 4*gg + r;                                           \
      _Pragma("unroll")                                                            \
      for(int vt=0;vt<4;++vt)                                                      \
        aout[(long)row_*D_MODEL + hd*HD + vt*16 + cc] =                            \
          __builtin_bit_cast(unsigned short, (__bf16)(acc_[vt][r] * inv_));        \
    }                                                                              \
  }

  OUTQ(accB, rsB, q0B);
  OUTQ(accA, rsA, q0A);

  #undef STAGE_K
  #undef VLOAD
  #undef VWRITE
  #undef QPART
  #undef TILE
  #undef OUTQ
}

extern "C" void kernel_launch(void* const* d_in, const int* in_sizes, int n_in,
                              void* d_out, int out_size, void* d_ws, size_t ws_size,
                              hipStream_t stream){
  (void)in_sizes; (void)n_in; (void)out_size; (void)ws_size;
  const float* x    = (const float*)d_in[0];
  const float* wqkv = (const float*)d_in[1];
  const float* wout = (const float*)d_in[2];
  char* ws = (char*)d_ws;
  unsigned short* xb    = (unsigned short*)(ws);                 //  8 MB
  unsigned short* wqkvb = (unsigned short*)(ws + (8u  << 20));   //  6 MB
  unsigned short* woutb = (unsigned short*)(ws + (14u << 20));   //  2 MB
  unsigned short* qkvb  = (unsigned short*)(ws + (16u << 20));   // 24 MB
  unsigned short* attnb = (unsigned short*)(ws + (40u << 20));   //  8 MB
  float* out = (float*)d_out;

  cvt_f32_bf16<<<(T_SEQ*D_MODEL/4 + 255)/256, 256, 0, stream>>>((const float4*)x,    (u16x4*)xb,    T_SEQ*D_MODEL/4);
  cvt_f32_bf16<<<(E3*D_MODEL/4   + 255)/256, 256, 0, stream>>>((const float4*)wqkv, (u16x4*)wqkvb, E3*D_MODEL/4);
  cvt_f32_bf16<<<(D_MODEL*D_MODEL/4 + 255)/256, 256, 0, stream>>>((const float4*)wout, (u16x4*)woutb, D_MODEL*D_MODEL/4);

  dim3 g1(E3/128, T_SEQ/128);
  gemm_bt<1,1><<<g1, 256, 0, stream>>>(xb, wqkvb, qkvb, T_SEQ, E3, D_MODEL);

  attn_fused<<<dim3(32*NH), 256, 0, stream>>>(qkvb, attnb);

  dim3 g3(D_MODEL/128, T_SEQ/128);
  gemm_bt<0,0><<<g3, 256, 0, stream>>>(attnb, woutb, out, T_SEQ, D_MODEL, D_MODEL);
}

// Round 5
// 172.370 us; speedup vs baseline: 1.0312x; 1.0312x over previous
//
#include <hip/hip_runtime.h>

#define T_SEQ   4096
#define D_MODEL 1024
#define NH      16
#define HD      64
#define E3      3072
// 0.125 * log2(e): folded into Q in the QKV-GEMM epilogue; softmax uses exp2 directly
#define QSCL    0.18033688011112042f
#define CLMP    14.426950408889634f

using u32x2  = __attribute__((ext_vector_type(2))) unsigned int;
using u32x4  = __attribute__((ext_vector_type(4))) unsigned int;
using u16x4  = __attribute__((ext_vector_type(4))) unsigned short;
using f32x4  = __attribute__((ext_vector_type(4))) float;
using bf16x8 = __attribute__((ext_vector_type(8))) __bf16;

__device__ __forceinline__ unsigned short f2bf(float f){
  unsigned int u = __builtin_bit_cast(unsigned int, f);
  u += 0x7fffu + ((u >> 16) & 1u);          // RNE
  return (unsigned short)(u >> 16);
}

__device__ __forceinline__ void gload_lds16(const void* g, void* l){
  __builtin_amdgcn_global_load_lds((const __attribute__((address_space(1))) void*)g,
                                   (__attribute__((address_space(3))) void*)l, 16, 0, 0);
}

// ---------------- fp32 -> bf16 convert ----------------
__global__ __launch_bounds__(256) void cvt_f32_bf16(const float4* __restrict__ in,
                                                    u16x4* __restrict__ out, int n4){
  int i = blockIdx.x * 256 + threadIdx.x;
  if(i < n4){
    float4 v = in[i];
    u16x4 o = { f2bf(v.x), f2bf(v.y), f2bf(v.z), f2bf(v.w) };
    out[i] = o;
  }
}

// ---------------- C = A * B^T  (A[M,K], B[N,K] row-major, bf16 in, fp32 acc) --------
template<int OUT_BF16, int QSCALE>
__global__ __launch_bounds__(256) void gemm_bt(const unsigned short* __restrict__ A,
                                               const unsigned short* __restrict__ B,
                                               void* __restrict__ Cv,
                                               int M, int N, int K){
  __shared__ unsigned short As[128*32];
  __shared__ unsigned short Bs[128*32];
  const int t    = threadIdx.x;
  const int lane = t & 63;
  const int w    = t >> 6;
  const int brow = blockIdx.y * 128;
  const int bcol = blockIdx.x * 128;
  const int wrow = (w >> 1) * 64;
  const int wcol = (w & 1) * 64;
  const int cc = lane & 15;
  const int gg = lane >> 4;

  f32x4 acc[4][4];
  #pragma unroll
  for(int m=0;m<4;++m)
    #pragma unroll
    for(int n=0;n<4;++n)
      acc[m][n] = (f32x4){0.f,0.f,0.f,0.f};

  const int srow = t >> 2;
  const int sk   = (t & 3) * 8;
  const long aBase = (long)(brow + srow) * K;
  const long bBase = (long)(bcol + srow) * K;

  for(int k0 = 0; k0 < K; k0 += 32){
    __syncthreads();
    gload_lds16(A + aBase + k0 + sk,               As + t*8);
    gload_lds16(A + aBase + 64*(long)K + k0 + sk,  As + 2048 + t*8);
    gload_lds16(B + bBase + k0 + sk,               Bs + t*8);
    gload_lds16(B + bBase + 64*(long)K + k0 + sk,  Bs + 2048 + t*8);
    __syncthreads();

    bf16x8 af[4], bfr[4];
    #pragma unroll
    for(int m=0;m<4;++m)
      af[m]  = *(const bf16x8*)((const char*)As + (wrow + m*16 + cc)*64 + gg*16);
    #pragma unroll
    for(int n=0;n<4;++n)
      bfr[n] = *(const bf16x8*)((const char*)Bs + (wcol + n*16 + cc)*64 + gg*16);
    #pragma unroll
    for(int m=0;m<4;++m)
      #pragma unroll
      for(int n=0;n<4;++n)
        acc[m][n] = __builtin_amdgcn_mfma_f32_16x16x32_bf16(af[m], bfr[n], acc[m][n], 0, 0, 0);
  }

  #pragma unroll
  for(int m=0;m<4;++m){
    #pragma unroll
    for(int n=0;n<4;++n){
      const int row0 = brow + wrow + m*16 + gg*4;
      const int col  = bcol + wcol + n*16 + cc;
      const float sc = (QSCALE && col < D_MODEL) ? QSCL : 1.0f;
      #pragma unroll
      for(int r=0;r<4;++r){
        if constexpr (OUT_BF16 != 0){
          ((unsigned short*)Cv)[(long)(row0 + r)*N + col] = f2bf(acc[m][n][r] * sc);
        } else {
          ((float*)Cv)[(long)(row0 + r)*N + col] = acc[m][n][r];
        }
      }
    }
  }
}

// ---------------- fused causal attention v5 ----------------
// block = (head, one 64-row q-block). 4 waves x 16 q-rows. KVBLK=64, double-buffered,
// registers-only P, 1 barrier/tile. Grid = 1024 = exactly 4 blocks/CU, all co-resident.
// qb permutation: same-CU blocks (bid stride 256 -> r stride 16) get complementary
// work {2b, 63-2b, 2b+1, 62-2b}: every CU hosts exactly 130 kv-tiles. No decay tail.
__global__ __launch_bounds__(256, 4) void attn_fused(const unsigned short* __restrict__ qkv,
                                                     unsigned short* __restrict__ aout){
  __shared__ unsigned short Ks[2][64*64];    // K: row=key (128B), chunk c holds d-oct c^(k&7)
  __shared__ unsigned short VTs[2][64*64];   // V^T: row=d (128B), chunk c holds k-oct c^((d>>1)&7)

  const int t    = threadIdx.x;
  const int lane = t & 63;
  const int w    = t >> 6;
  const int cc   = lane & 15;
  const int gg   = lane >> 4;

  const int bid  = blockIdx.x;
  const int hd   = bid & 15;
  const int r_   = bid >> 4;                 // 0..63
  const int s_   = r_ >> 4;                  // CU-slot class
  const int b_   = r_ & 15;
  const int qb   = (s_ == 0) ? 2*b_ : (s_ == 1) ? 63 - 2*b_
                 : (s_ == 2) ? 2*b_ + 1     : 62 - 2*b_;
  const int nkv  = qb + 1;
  const int q0w  = qb*64 + w*16;

  // Q fragments (pre-scaled by 0.125*log2e in GEMM epilogue)
  bf16x8 bq0 = *(const bf16x8*)(qkv + (long)(q0w+cc)*E3 + hd*HD +      gg*8);
  bf16x8 bq1 = *(const bf16x8*)(qkv + (long)(q0w+cc)*E3 + hd*HD + 32 + gg*8);

  f32x4 acc[4];
  #pragma unroll
  for(int vt=0;vt<4;++vt) acc[vt] = (f32x4){0.f,0.f,0.f,0.f};
  float rs = 0.f;

  // ---- hoisted LDS read pointers (kt/vt/buf are immediate offsets) ----
  const char* kp0  = (const char*)Ks  + cc*128 + ((gg ^ (cc&7)) << 4);  // d-octs 0..3
  const char* kp1  = kp0 + ((((gg ^ (cc&7)) ^ 4) - (gg ^ (cc&7))) << 4); // ^64: d-octs 4..7
  const int   va0  = cc*128 + (((gg>>1) ^ (cc>>1)) << 4) + (gg&1)*8;
  const char* vp00 = (const char*)VTs + va0;          // hh0, k-oct lo
  const char* vp01 = (const char*)VTs + (va0 ^ 32);   // hh0, k-oct hi
  const char* vp10 = (const char*)VTs + (va0 ^ 64);   // hh1, lo
  const char* vp11 = (const char*)VTs + (va0 ^ 96);   // hh1, hi

  // ---- staging precompute ----
  const long tileStride = 64L * E3;
  const int  s0  = t*16,            s1  = 4096 + t*16;
  const int  kr0 = s0 >> 7,         kr1 = s1 >> 7;
  const long kg0 = (long)kr0*E3 + D_MODEL + hd*HD + ((((s0>>4)&7) ^ (kr0&7)))*8;
  const long kg1 = (long)kr1*E3 + D_MODEL + hd*HD + ((((s1>>4)&7) ^ (kr1&7)))*8;
  const int  dp  = t & 31;
  const int  ko  = t >> 5;
  const long vg  = (long)(ko*8)*E3 + 2*D_MODEL + hd*HD + 2*dp;
  char* vwp = (char*)VTs + (2*dp)*128 + ((ko ^ (dp&7)) << 4);

  unsigned int vr[8];

  #define STAGE_K(kb_, BUF) do{                                                    \
    gload_lds16(qkv + kg0 + (kb_)*tileStride, (char*)Ks + (BUF)*8192 + s0);        \
    gload_lds16(qkv + kg1 + (kb_)*tileStride, (char*)Ks + (BUF)*8192 + s1);        \
  }while(0)

  #define VLOAD(kb_) do{                                                           \
    const unsigned short* vb_ = qkv + vg + (kb_)*tileStride;                       \
    _Pragma("unroll")                                                              \
    for(int j=0;j<8;++j) vr[j] = *(const unsigned int*)(vb_ + (long)j*E3);         \
  }while(0)

  #define VWRITE(BUF) do{                                                          \
    u32x4 lo_, hi_;                                                                \
    _Pragma("unroll")                                                              \
    for(int j=0;j<4;++j){                                                          \
      lo_[j] = __builtin_amdgcn_perm(vr[2*j+1], vr[2*j], 0x05040100u);             \
      hi_[j] = __builtin_amdgcn_perm(vr[2*j+1], vr[2*j], 0x07060302u);             \
    }                                                                              \
    *(u32x4*)(vwp + (BUF)*8192      ) = lo_;                                       \
    *(u32x4*)(vwp + (BUF)*8192 + 128) = hi_;                                       \
  }while(0)

  #define TILE(kb_, BUF)                                                           \
  {                                                                                \
    const bool pf_   = ((kb_) + 1 < nkv);                                          \
    const bool last_ = ((kb_) == nkv - 1);                                         \
    if(pf_){ STAGE_K((kb_)+1, (BUF)^1); VLOAD((kb_)+1); }                          \
    float pkf[4][4];                                                               \
    _Pragma("unroll")                                                              \
    for(int kt=0; kt<4; ++kt){                                                     \
      if(!last_ || kt <= w){                                                       \
        bf16x8 a0 = *(const bf16x8*)(kp0 + (BUF)*8192 + kt*2048);                  \
        bf16x8 a1 = *(const bf16x8*)(kp1 + (BUF)*8192 + kt*2048);                  \
        __builtin_amdgcn_s_setprio(1);                                             \
        f32x4 s = __builtin_amdgcn_mfma_f32_16x16x32_bf16(a0, bq0,                 \
                    (f32x4){0.f,0.f,0.f,0.f}, 0,0,0);                              \
        s = __builtin_amdgcn_mfma_f32_16x16x32_bf16(a1, bq1, s, 0,0,0);            \
        __builtin_amdgcn_s_setprio(0);                                             \
        const bool diag_ = last_ && (kt == w);                                     \
        _Pragma("unroll")                                                          \
        for(int rr=0;rr<4;++rr){                                                   \
          float sv = __builtin_amdgcn_fmed3f(s[rr], -CLMP, CLMP);                  \
          float p  = __builtin_exp2f(sv);                                          \
          if(diag_ && (4*gg + rr > cc)) p = 0.f;                                   \
          pkf[kt][rr] = p;                                                         \
          rs += p;                                                                 \
        }                                                                          \
      } else {                                                                     \
        _Pragma("unroll")                                                          \
        for(int rr=0;rr<4;++rr) pkf[kt][rr] = 0.f;                                 \
      }                                                                            \
    }                                                                              \
    bf16x8 pa0 = (bf16x8){ (__bf16)pkf[0][0],(__bf16)pkf[0][1],(__bf16)pkf[0][2],  \
      (__bf16)pkf[0][3],(__bf16)pkf[1][0],(__bf16)pkf[1][1],(__bf16)pkf[1][2],     \
      (__bf16)pkf[1][3] };                                                         \
    bf16x8 pa1 = (bf16x8){ (__bf16)pkf[2][0],(__bf16)pkf[2][1],(__bf16)pkf[2][2],  \
      (__bf16)pkf[2][3],(__bf16)pkf[3][0],(__bf16)pkf[3][1],(__bf16)pkf[3][2],     \
      (__bf16)pkf[3][3] };                                                         \
    _Pragma("unroll")                                                              \
    for(int hh=0; hh<2; ++hh){                                                     \
      if(!last_ || 2*hh <= w){                                                     \
        const char* vl_ = hh ? vp10 : vp00;                                        \
        const char* vh_ = hh ? vp11 : vp01;                                        \
        __builtin_amdgcn_s_setprio(1);                                             \
        _Pragma("unroll")                                                          \
        for(int vt=0; vt<4; ++vt){                                                 \
          u32x2 lo = *(const u32x2*)(vl_ + (BUF)*8192 + vt*2048);                  \
          u32x2 hi = *(const u32x2*)(vh_ + (BUF)*8192 + vt*2048);                  \
          bf16x8 bv = __builtin_bit_cast(bf16x8,(u32x4){lo[0],lo[1],hi[0],hi[1]}); \
          acc[vt] = __builtin_amdgcn_mfma_f32_16x16x32_bf16(hh ? pa1 : pa0, bv,    \
                       acc[vt], 0,0,0);                                            \
        }                                                                          \
        __builtin_amdgcn_s_setprio(0);                                             \
      }                                                                            \
    }                                                                              \
    if(pf_) VWRITE((BUF)^1);                                                       \
    __syncthreads();                                                               \
  }

  STAGE_K(0, 0);
  VLOAD(0);
  VWRITE(0);
  __syncthreads();

  int kv = 0;
  while(kv + 2 <= nkv){
    TILE(kv,   0);
    TILE(kv+1, 1);
    kv += 2;
  }
  if(kv < nkv) TILE(kv, 0);

  // rowsum: lane holds partial for q=cc over its keys; reduce across gg (bits 4,5)
  rs += __shfl_xor(rs, 16);
  rs += __shfl_xor(rs, 32);

  #pragma unroll
  for(int rr=0;rr<4;++rr){
    const float inv = 1.0f / __shfl(rs, 4*gg + rr);
    const int row = q0w + 4*gg + rr;
    #pragma unroll
    for(int vt=0;vt<4;++vt)
      aout[(long)row*D_MODEL + hd*HD + vt*16 + cc] =
        __builtin_bit_cast(unsigned short, (__bf16)(acc[vt][rr] * inv));
  }
  #undef STAGE_K
  #undef VLOAD
  #undef VWRITE
  #undef TILE
}

extern "C" void kernel_launch(void* const* d_in, const int* in_sizes, int n_in,
                              void* d_out, int out_size, void* d_ws, size_t ws_size,
                              hipStream_t stream){
  (void)in_sizes; (void)n_in; (void)out_size; (void)ws_size;
  const float* x    = (const float*)d_in[0];
  const float* wqkv = (const float*)d_in[1];
  const float* wout = (const float*)d_in[2];
  char* ws = (char*)d_ws;
  unsigned short* xb    = (unsigned short*)(ws);                 //  8 MB
  unsigned short* wqkvb = (unsigned short*)(ws + (8u  << 20));   //  6 MB
  unsigned short* woutb = (unsigned short*)(ws + (14u << 20));   //  2 MB
  unsigned short* qkvb  = (unsigned short*)(ws + (16u << 20));   // 24 MB
  unsigned short* attnb = (unsigned short*)(ws + (40u << 20));   //  8 MB
  float* out = (float*)d_out;

  cvt_f32_bf16<<<(T_SEQ*D_MODEL/4 + 255)/256, 256, 0, stream>>>((const float4*)x,    (u16x4*)xb,    T_SEQ*D_MODEL/4);
  cvt_f32_bf16<<<(E3*D_MODEL/4   + 255)/256, 256, 0, stream>>>((const float4*)wqkv, (u16x4*)wqkvb, E3*D_MODEL/4);
  cvt_f32_bf16<<<(D_MODEL*D_MODEL/4 + 255)/256, 256, 0, stream>>>((const float4*)wout, (u16x4*)woutb, D_MODEL*D_MODEL/4);

  dim3 g1(E3/128, T_SEQ/128);
  gemm_bt<1,1><<<g1, 256, 0, stream>>>(xb, wqkvb, qkvb, T_SEQ, E3, D_MODEL);

  attn_fused<<<dim3(64*NH), 256, 0, stream>>>(qkvb, attnb);

  dim3 g3(D_MODEL/128, T_SEQ/128);
  gemm_bt<0,0><<<g3, 256, 0, stream>>>(attnb, woutb, out, T_SEQ, D_MODEL, D_MODEL);
}